// Round 2
// baseline (3114.059 us; speedup 1.0000x reference)
//
#include <hip/hip_runtime.h>
#include <stdint.h>
#include <math.h>

#define T_TOKENS 8192
#define H_DIM    2048
#define I_DIM    16384
#define NEXP     5
#define RANK     16
#define LORA_SCALE 2.0f

typedef __attribute__((ext_vector_type(8))) short bf16x8;   // 8 bf16 in 4 VGPRs
typedef __attribute__((ext_vector_type(4))) float f32x4;

typedef const __attribute__((address_space(1))) void gv_t;  // global
typedef __attribute__((address_space(3))) void lv_t;        // LDS

__device__ __forceinline__ uint16_t f2bf(float f) {
  union { uint32_t u; float f; } v; v.f = f;
  uint32_t u = v.u;
  return (uint16_t)((u + 0x7fffu + ((u >> 16) & 1u)) >> 16);
}
__device__ __forceinline__ uint32_t pack2(float lo, float hi) {
  return (uint32_t)f2bf(lo) | ((uint32_t)f2bf(hi) << 16);
}
__device__ __forceinline__ float gelu_tanh(float x) {
  float x3 = x * x * x;
  float inner = 0.7978845608028654f * (x + 0.044715f * x3);
  return 0.5f * x * (1.0f + tanhf(inner));
}

// ---------------------------------------------------------------------------
// Kernel 0: fp32 -> bf16 conversion (8 elements / thread)
// ---------------------------------------------------------------------------
__global__ __launch_bounds__(256) void cvt_kernel(
    const float* __restrict__ src, uint16_t* __restrict__ dst, int n8)
{
  int i = blockIdx.x * 256 + threadIdx.x;
  if (i >= n8) return;
  float4 a = ((const float4*)src)[2 * i];
  float4 b = ((const float4*)src)[2 * i + 1];
  uint4 o;
  o.x = pack2(a.x, a.y);
  o.y = pack2(a.z, a.w);
  o.z = pack2(b.x, b.y);
  o.w = pack2(b.z, b.w);
  ((uint4*)dst)[i] = o;
}

// ---------------------------------------------------------------------------
// Kernel 1: router logits -> softmax stats + per-token rank-16 LoRA (fp32 in).
// One block (256 threads) per token. Thread t owns x[t*8 .. t*8+8).
// Writes the fp32 LoRA correction into `lora_out` (== d_out).
// ---------------------------------------------------------------------------
__global__ __launch_bounds__(256) void router_lora_kernel(
    const float* __restrict__ X,     // [T, H] fp32
    const float* __restrict__ RW,    // [5, H]
    const float* __restrict__ LA,    // [4, 16, H]
    const float* __restrict__ LB,    // [4, H, 16]
    float* __restrict__ lora_out,    // [T, H] fp32
    float* __restrict__ accum)       // [10] fp32 (probs sum, count sum)
{
  const int token = blockIdx.x;
  const int t = threadIdx.x;
  const int lane = t & 63, wid = t >> 6;

  __shared__ float red5[NEXP][4];
  __shared__ float logits_s[NEXP];
  __shared__ float tred[4][RANK];
  __shared__ float tvec[RANK];

  const float* x = X + (size_t)token * H_DIM;
  float4 xa = ((const float4*)x)[2 * t];
  float4 xb = ((const float4*)x)[2 * t + 1];
  float xv[8] = {xa.x, xa.y, xa.z, xa.w, xb.x, xb.y, xb.z, xb.w};

  // ---- logits ----
  float part[NEXP];
  #pragma unroll
  for (int e = 0; e < NEXP; e++) {
    const float* r = RW + e * H_DIM + t * 8;
    float4 ra = ((const float4*)r)[0];
    float4 rb = ((const float4*)r)[1];
    part[e] = xv[0]*ra.x + xv[1]*ra.y + xv[2]*ra.z + xv[3]*ra.w
            + xv[4]*rb.x + xv[5]*rb.y + xv[6]*rb.z + xv[7]*rb.w;
  }
  #pragma unroll
  for (int e = 0; e < NEXP; e++)
    #pragma unroll
    for (int off = 32; off > 0; off >>= 1)
      part[e] += __shfl_down(part[e], off, 64);
  if (lane == 0) {
    #pragma unroll
    for (int e = 0; e < NEXP; e++) red5[e][wid] = part[e];
  }
  __syncthreads();
  if (t == 0) {
    #pragma unroll
    for (int e = 0; e < NEXP; e++)
      logits_s[e] = red5[e][0] + red5[e][1] + red5[e][2] + red5[e][3];
  }
  __syncthreads();

  float lg[NEXP];
  #pragma unroll
  for (int e = 0; e < NEXP; e++) lg[e] = logits_s[e];
  int sel = 0; float best = lg[0];
  #pragma unroll
  for (int e = 1; e < NEXP; e++) if (lg[e] > best) { best = lg[e]; sel = e; }

  if (t == 0) {
    float s = 0.f, p[NEXP];
    #pragma unroll
    for (int e = 0; e < NEXP; e++) { p[e] = expf(lg[e] - best); s += p[e]; }
    float inv = 1.0f / s;
    #pragma unroll
    for (int e = 0; e < NEXP; e++) atomicAdd(&accum[e], p[e] * inv);
    atomicAdd(&accum[NEXP + sel], 1.0f);
  }

  // ---- LoRA correction (block-uniform branch) ----
  float outv[8] = {0.f,0.f,0.f,0.f,0.f,0.f,0.f,0.f};
  if (sel > 0) {
    const int e = sel - 1;
    const float* A = LA + (size_t)e * RANK * H_DIM;
    float tp[RANK];
    #pragma unroll
    for (int r = 0; r < RANK; r++) {
      const float* ar = A + r * H_DIM + t * 8;
      float4 a0 = ((const float4*)ar)[0];
      float4 a1 = ((const float4*)ar)[1];
      tp[r] = xv[0]*a0.x + xv[1]*a0.y + xv[2]*a0.z + xv[3]*a0.w
            + xv[4]*a1.x + xv[5]*a1.y + xv[6]*a1.z + xv[7]*a1.w;
    }
    #pragma unroll
    for (int r = 0; r < RANK; r++)
      #pragma unroll
      for (int off = 32; off > 0; off >>= 1)
        tp[r] += __shfl_down(tp[r], off, 64);
    if (lane == 0) {
      #pragma unroll
      for (int r = 0; r < RANK; r++) tred[wid][r] = tp[r];
    }
    __syncthreads();
    if (t < RANK) tvec[t] = tred[0][t] + tred[1][t] + tred[2][t] + tred[3][t];
    __syncthreads();

    const float* Bm = LB + (size_t)e * H_DIM * RANK;
    #pragma unroll
    for (int j = 0; j < 8; j++) {
      int h = t * 8 + j;
      const float* brow = Bm + h * RANK;
      float s = 0.f;
      #pragma unroll
      for (int r = 0; r < RANK; r += 4) {
        float4 b = ((const float4*)(brow + r))[0];
        s += tvec[r]*b.x + tvec[r+1]*b.y + tvec[r+2]*b.z + tvec[r+3]*b.w;
      }
      outv[j] = LORA_SCALE * s;
    }
  }
  float4* dst = (float4*)(lora_out + (size_t)token * H_DIM + t * 8);
  dst[0] = make_float4(outv[0], outv[1], outv[2], outv[3]);
  dst[1] = make_float4(outv[4], outv[5], outv[6], outv[7]);
}

// ---------------------------------------------------------------------------
// Kernel 2: act = gelu(X @ Wg^T) * (X @ Wu^T)   [m97-style 128x128 tile, bf16]
// Wg/Wu stored [I, H] row-major == B^T form. 256 thr = 4 waves (2x2 of 64x64).
// ---------------------------------------------------------------------------
__global__ __launch_bounds__(256, 2) void gemm_gateup_kernel(
    const uint16_t* __restrict__ X,    // [T, H] bf16
    const uint16_t* __restrict__ Wg,   // [I, H] bf16
    const uint16_t* __restrict__ Wu,   // [I, H] bf16
    uint16_t* __restrict__ act)        // [T, I] bf16
{
  const int K = H_DIM;
  __shared__ __align__(16) uint16_t sa[128 * 32];
  __shared__ __align__(16) uint16_t sg[128 * 32];
  __shared__ __align__(16) uint16_t su[128 * 32];

  const int t = threadIdx.x;
  const int m0 = blockIdx.y * 128;
  const int n0 = blockIdx.x * 128;
  const int lane = t & 63;
  const int wid = t >> 6;
  const int wm = (wid >> 1) * 64;
  const int wn = (wid & 1) * 64;
  const int fr = lane & 15;
  const int fk = (lane >> 4) * 8;

  const int c0 = t, c1 = t + 256;   // 16B chunks: row=c>>2, subchunk=c&3
  const uint16_t* ga0 = X  + (size_t)(m0 + (c0 >> 2)) * K + (c0 & 3) * 8;
  const uint16_t* ga1 = X  + (size_t)(m0 + (c1 >> 2)) * K + (c1 & 3) * 8;
  const uint16_t* gg0 = Wg + (size_t)(n0 + (c0 >> 2)) * K + (c0 & 3) * 8;
  const uint16_t* gg1 = Wg + (size_t)(n0 + (c1 >> 2)) * K + (c1 & 3) * 8;
  const uint16_t* gu0 = Wu + (size_t)(n0 + (c0 >> 2)) * K + (c0 & 3) * 8;
  const uint16_t* gu1 = Wu + (size_t)(n0 + (c1 >> 2)) * K + (c1 & 3) * 8;

  f32x4 accg[4][4], accu[4][4];
  #pragma unroll
  for (int i = 0; i < 4; i++)
    #pragma unroll
    for (int j = 0; j < 4; j++) {
      accg[i][j] = (f32x4){0.f, 0.f, 0.f, 0.f};
      accu[i][j] = (f32x4){0.f, 0.f, 0.f, 0.f};
    }

  for (int k0 = 0; k0 < K; k0 += 32) {
    __syncthreads();
    __builtin_amdgcn_global_load_lds((gv_t*)ga0, (lv_t*)(sa + c0 * 8), 16, 0, 0);
    __builtin_amdgcn_global_load_lds((gv_t*)ga1, (lv_t*)(sa + c1 * 8), 16, 0, 0);
    __builtin_amdgcn_global_load_lds((gv_t*)gg0, (lv_t*)(sg + c0 * 8), 16, 0, 0);
    __builtin_amdgcn_global_load_lds((gv_t*)gg1, (lv_t*)(sg + c1 * 8), 16, 0, 0);
    __builtin_amdgcn_global_load_lds((gv_t*)gu0, (lv_t*)(su + c0 * 8), 16, 0, 0);
    __builtin_amdgcn_global_load_lds((gv_t*)gu1, (lv_t*)(su + c1 * 8), 16, 0, 0);
    ga0 += 32; ga1 += 32; gg0 += 32; gg1 += 32; gu0 += 32; gu1 += 32;
    __syncthreads();

    bf16x8 af[4], gf[4], uf[4];
    #pragma unroll
    for (int mi = 0; mi < 4; mi++)
      af[mi] = *(const bf16x8*)(sa + (wm + mi * 16 + fr) * 32 + fk);
    #pragma unroll
    for (int ni = 0; ni < 4; ni++) {
      gf[ni] = *(const bf16x8*)(sg + (wn + ni * 16 + fr) * 32 + fk);
      uf[ni] = *(const bf16x8*)(su + (wn + ni * 16 + fr) * 32 + fk);
    }
    #pragma unroll
    for (int mi = 0; mi < 4; mi++)
      #pragma unroll
      for (int ni = 0; ni < 4; ni++) {
        accg[mi][ni] = __builtin_amdgcn_mfma_f32_16x16x32_bf16(af[mi], gf[ni], accg[mi][ni], 0, 0, 0);
        accu[mi][ni] = __builtin_amdgcn_mfma_f32_16x16x32_bf16(af[mi], uf[ni], accu[mi][ni], 0, 0, 0);
      }
  }

  // C/D layout: col = lane&15, row = (lane>>4)*4 + reg  [m89-verified]
  const int rbase = (lane >> 4) * 4;
  const int cbase = lane & 15;
  #pragma unroll
  for (int mi = 0; mi < 4; mi++)
    #pragma unroll
    for (int ni = 0; ni < 4; ni++)
      #pragma unroll
      for (int i = 0; i < 4; i++) {
        int row = m0 + wm + mi * 16 + rbase + i;
        int col = n0 + wn + ni * 16 + cbase;
        float g = accg[mi][ni][i];
        float u = accu[mi][ni][i];
        act[(size_t)row * I_DIM + col] = f2bf(gelu_tanh(g) * u);
      }
}

// ---------------------------------------------------------------------------
// Kernel 3: out = act @ Wd^T + lora   (Wd stored [H, I] == B^T form)
// `lora` aliases `out` (read-then-overwrite per element by same thread).
// ---------------------------------------------------------------------------
__global__ __launch_bounds__(256, 2) void gemm_down_kernel(
    const uint16_t* __restrict__ Act,  // [T, I] bf16
    const uint16_t* __restrict__ Wd,   // [H, I] bf16
    float* __restrict__ out)           // [T, H] fp32 (holds lora on entry)
{
  const int K = I_DIM;
  __shared__ __align__(16) uint16_t sa[128 * 32];
  __shared__ __align__(16) uint16_t sb[128 * 32];

  const int t = threadIdx.x;
  const int m0 = blockIdx.y * 128;
  const int n0 = blockIdx.x * 128;
  const int lane = t & 63;
  const int wid = t >> 6;
  const int wm = (wid >> 1) * 64;
  const int wn = (wid & 1) * 64;
  const int fr = lane & 15;
  const int fk = (lane >> 4) * 8;

  const int c0 = t, c1 = t + 256;
  const uint16_t* ga0 = Act + (size_t)(m0 + (c0 >> 2)) * K + (c0 & 3) * 8;
  const uint16_t* ga1 = Act + (size_t)(m0 + (c1 >> 2)) * K + (c1 & 3) * 8;
  const uint16_t* gb0 = Wd  + (size_t)(n0 + (c0 >> 2)) * K + (c0 & 3) * 8;
  const uint16_t* gb1 = Wd  + (size_t)(n0 + (c1 >> 2)) * K + (c1 & 3) * 8;

  f32x4 acc[4][4];
  #pragma unroll
  for (int i = 0; i < 4; i++)
    #pragma unroll
    for (int j = 0; j < 4; j++) acc[i][j] = (f32x4){0.f, 0.f, 0.f, 0.f};

  for (int k0 = 0; k0 < K; k0 += 32) {
    __syncthreads();
    __builtin_amdgcn_global_load_lds((gv_t*)ga0, (lv_t*)(sa + c0 * 8), 16, 0, 0);
    __builtin_amdgcn_global_load_lds((gv_t*)ga1, (lv_t*)(sa + c1 * 8), 16, 0, 0);
    __builtin_amdgcn_global_load_lds((gv_t*)gb0, (lv_t*)(sb + c0 * 8), 16, 0, 0);
    __builtin_amdgcn_global_load_lds((gv_t*)gb1, (lv_t*)(sb + c1 * 8), 16, 0, 0);
    ga0 += 32; ga1 += 32; gb0 += 32; gb1 += 32;
    __syncthreads();

    bf16x8 af[4], bfr[4];
    #pragma unroll
    for (int mi = 0; mi < 4; mi++)
      af[mi] = *(const bf16x8*)(sa + (wm + mi * 16 + fr) * 32 + fk);
    #pragma unroll
    for (int ni = 0; ni < 4; ni++)
      bfr[ni] = *(const bf16x8*)(sb + (wn + ni * 16 + fr) * 32 + fk);
    #pragma unroll
    for (int mi = 0; mi < 4; mi++)
      #pragma unroll
      for (int ni = 0; ni < 4; ni++)
        acc[mi][ni] = __builtin_amdgcn_mfma_f32_16x16x32_bf16(af[mi], bfr[ni], acc[mi][ni], 0, 0, 0);
  }

  const int rbase = (lane >> 4) * 4;
  const int cbase = lane & 15;
  #pragma unroll
  for (int mi = 0; mi < 4; mi++)
    #pragma unroll
    for (int ni = 0; ni < 4; ni++)
      #pragma unroll
      for (int i = 0; i < 4; i++) {
        int row = m0 + wm + mi * 16 + rbase + i;
        int col = n0 + wn + ni * 16 + cbase;
        size_t idx = (size_t)row * H_DIM + col;
        out[idx] = acc[mi][ni][i] + out[idx];
      }
}

// ---------------------------------------------------------------------------
// Kernel 4: aux loss scalar (fp32)
// ---------------------------------------------------------------------------
__global__ void aux_kernel(const float* __restrict__ accum,
                           float* __restrict__ out_aux)
{
  if (threadIdx.x == 0 && blockIdx.x == 0) {
    float s = 0.f;
    #pragma unroll
    for (int e = 0; e < NEXP; e++)
      s += (accum[e] / (float)T_TOKENS) * (accum[NEXP + e] / (float)T_TOKENS);
    out_aux[0] = s * (float)NEXP * 0.01f;
  }
}

// ---------------------------------------------------------------------------
extern "C" void kernel_launch(void* const* d_in, const int* in_sizes, int n_in,
                              void* d_out, int out_size, void* d_ws, size_t ws_size,
                              hipStream_t stream) {
  const float* X  = (const float*)d_in[0];  // hidden_states [4,2048,2048] fp32
  const float* RW = (const float*)d_in[1];  // router_w [5,2048]
  const float* Wg = (const float*)d_in[2];  // gate_w [16384,2048]
  const float* Wu = (const float*)d_in[3];  // up_w [16384,2048]
  const float* Wd = (const float*)d_in[4];  // down_w [2048,16384]
  const float* LA = (const float*)d_in[5];  // lora_A [4,16,2048]
  const float* LB = (const float*)d_in[6];  // lora_B [4,2048,16]
  float* out = (float*)d_out;               // [4,2048,2048] fp32 + 1 aux

  char* ws = (char*)d_ws;
  uint16_t* Xb    = (uint16_t*)(ws);                         // 32 MiB bf16 [T,H]
  uint16_t* Wgb   = (uint16_t*)(ws + (size_t)32  * 1048576); // 64 MiB bf16 [I,H]
  uint16_t* Wub   = (uint16_t*)(ws + (size_t)96  * 1048576); // 64 MiB
  uint16_t* Wdb   = (uint16_t*)(ws + (size_t)160 * 1048576); // 64 MiB [H,I]
  uint16_t* act   = (uint16_t*)(ws + (size_t)224 * 1048576); // 256 MiB bf16 [T,I]
  float*    accum = (float*)   (ws + (size_t)480 * 1048576); // 16 floats

  hipMemsetAsync(accum, 0, 16 * sizeof(float), stream);

  const int nX = T_TOKENS * H_DIM, nW = I_DIM * H_DIM;
  cvt_kernel<<<nX / 8 / 256, 256, 0, stream>>>(X,  Xb,  nX / 8);
  cvt_kernel<<<nW / 8 / 256, 256, 0, stream>>>(Wg, Wgb, nW / 8);
  cvt_kernel<<<nW / 8 / 256, 256, 0, stream>>>(Wu, Wub, nW / 8);
  cvt_kernel<<<nW / 8 / 256, 256, 0, stream>>>(Wd, Wdb, nW / 8);

  router_lora_kernel<<<T_TOKENS, 256, 0, stream>>>(X, RW, LA, LB, out, accum);
  gemm_gateup_kernel<<<dim3(I_DIM / 128, T_TOKENS / 128), 256, 0, stream>>>(Xb, Wgb, Wub, act);
  gemm_down_kernel<<<dim3(H_DIM / 128, T_TOKENS / 128), 256, 0, stream>>>(act, Wdb, out);
  aux_kernel<<<1, 64, 0, stream>>>(accum, out + (size_t)T_TOKENS * H_DIM);
}

// Round 3
// 3035.118 us; speedup vs baseline: 1.0260x; 1.0260x over previous
//
#include <hip/hip_runtime.h>
#include <stdint.h>
#include <math.h>

#define T_TOKENS 8192
#define H_DIM    2048
#define I_DIM    16384
#define NEXP     5
#define RANK     16
#define LORA_SCALE 2.0f

typedef __attribute__((ext_vector_type(8))) short bf16x8;   // 8 bf16 in 4 VGPRs
typedef __attribute__((ext_vector_type(4))) float f32x4;

typedef const __attribute__((address_space(1))) void gv_t;  // global
typedef __attribute__((address_space(3))) void lv_t;        // LDS

__device__ __forceinline__ uint16_t f2bf(float f) {
  union { uint32_t u; float f; } v; v.f = f;
  uint32_t u = v.u;
  return (uint16_t)((u + 0x7fffu + ((u >> 16) & 1u)) >> 16);
}
__device__ __forceinline__ uint32_t pack2(float lo, float hi) {
  return (uint32_t)f2bf(lo) | ((uint32_t)f2bf(hi) << 16);
}
// gelu_tanh(x) == x * sigmoid(2*0.7978845608*(x + 0.044715 x^3)); __expf -> v_exp_f32
__device__ __forceinline__ float gelu_fast(float x) {
  float x3 = x * x * x;
  float z = 1.5957691216057308f * (x + 0.044715f * x3);
  return x / (1.0f + __expf(-z));
}

// ---------------------------------------------------------------------------
// Kernel 0: fp32 -> bf16 conversion (8 elements / thread)
// ---------------------------------------------------------------------------
__global__ __launch_bounds__(256) void cvt_kernel(
    const float* __restrict__ src, uint16_t* __restrict__ dst, int n8)
{
  int i = blockIdx.x * 256 + threadIdx.x;
  if (i >= n8) return;
  float4 a = ((const float4*)src)[2 * i];
  float4 b = ((const float4*)src)[2 * i + 1];
  uint4 o;
  o.x = pack2(a.x, a.y);
  o.y = pack2(a.z, a.w);
  o.z = pack2(b.x, b.y);
  o.w = pack2(b.z, b.w);
  ((uint4*)dst)[i] = o;
}

// ---------------------------------------------------------------------------
// Kernel 1: router logits -> softmax stats + rank-16 LoRA (fp32 in).
// Also emits the bf16 copy of X (fuses the X cvt pass).
// One block (256 threads) per token; thread t owns x[t*8 .. t*8+8).
// ---------------------------------------------------------------------------
__global__ __launch_bounds__(256) void router_lora_kernel(
    const float* __restrict__ X,     // [T, H] fp32
    const float* __restrict__ RW,    // [5, H]
    const float* __restrict__ LA,    // [4, 16, H]
    const float* __restrict__ LB,    // [4, H, 16]
    float* __restrict__ lora_out,    // [T, H] fp32  (== d_out)
    uint16_t* __restrict__ Xb,       // [T, H] bf16
    float* __restrict__ accum)       // [10] fp32 (probs sum, count sum)
{
  const int token = blockIdx.x;
  const int t = threadIdx.x;
  const int lane = t & 63, wid = t >> 6;

  __shared__ float red5[NEXP][4];
  __shared__ float logits_s[NEXP];
  __shared__ float tred[4][RANK];
  __shared__ float tvec[RANK];

  const float* x = X + (size_t)token * H_DIM;
  float4 xa = ((const float4*)x)[2 * t];
  float4 xb = ((const float4*)x)[2 * t + 1];
  float xv[8] = {xa.x, xa.y, xa.z, xa.w, xb.x, xb.y, xb.z, xb.w};

  // bf16 copy of X
  {
    uint4 o;
    o.x = pack2(xv[0], xv[1]);
    o.y = pack2(xv[2], xv[3]);
    o.z = pack2(xv[4], xv[5]);
    o.w = pack2(xv[6], xv[7]);
    ((uint4*)(Xb + (size_t)token * H_DIM))[t] = o;
  }

  // ---- logits ----
  float part[NEXP];
  #pragma unroll
  for (int e = 0; e < NEXP; e++) {
    const float* r = RW + e * H_DIM + t * 8;
    float4 ra = ((const float4*)r)[0];
    float4 rb = ((const float4*)r)[1];
    part[e] = xv[0]*ra.x + xv[1]*ra.y + xv[2]*ra.z + xv[3]*ra.w
            + xv[4]*rb.x + xv[5]*rb.y + xv[6]*rb.z + xv[7]*rb.w;
  }
  #pragma unroll
  for (int e = 0; e < NEXP; e++)
    #pragma unroll
    for (int off = 32; off > 0; off >>= 1)
      part[e] += __shfl_down(part[e], off, 64);
  if (lane == 0) {
    #pragma unroll
    for (int e = 0; e < NEXP; e++) red5[e][wid] = part[e];
  }
  __syncthreads();
  if (t == 0) {
    #pragma unroll
    for (int e = 0; e < NEXP; e++)
      logits_s[e] = red5[e][0] + red5[e][1] + red5[e][2] + red5[e][3];
  }
  __syncthreads();

  float lg[NEXP];
  #pragma unroll
  for (int e = 0; e < NEXP; e++) lg[e] = logits_s[e];
  int sel = 0; float best = lg[0];
  #pragma unroll
  for (int e = 1; e < NEXP; e++) if (lg[e] > best) { best = lg[e]; sel = e; }

  if (t == 0) {
    float s = 0.f, p[NEXP];
    #pragma unroll
    for (int e = 0; e < NEXP; e++) { p[e] = __expf(lg[e] - best); s += p[e]; }
    float inv = 1.0f / s;
    #pragma unroll
    for (int e = 0; e < NEXP; e++) atomicAdd(&accum[e], p[e] * inv);
    atomicAdd(&accum[NEXP + sel], 1.0f);
  }

  // ---- LoRA correction (block-uniform branch) ----
  float outv[8] = {0.f,0.f,0.f,0.f,0.f,0.f,0.f,0.f};
  if (sel > 0) {
    const int e = sel - 1;
    const float* A = LA + (size_t)e * RANK * H_DIM;
    float tp[RANK];
    #pragma unroll
    for (int r = 0; r < RANK; r++) {
      const float* ar = A + r * H_DIM + t * 8;
      float4 a0 = ((const float4*)ar)[0];
      float4 a1 = ((const float4*)ar)[1];
      tp[r] = xv[0]*a0.x + xv[1]*a0.y + xv[2]*a0.z + xv[3]*a0.w
            + xv[4]*a1.x + xv[5]*a1.y + xv[6]*a1.z + xv[7]*a1.w;
    }
    #pragma unroll
    for (int r = 0; r < RANK; r++)
      #pragma unroll
      for (int off = 32; off > 0; off >>= 1)
        tp[r] += __shfl_down(tp[r], off, 64);
    if (lane == 0) {
      #pragma unroll
      for (int r = 0; r < RANK; r++) tred[wid][r] = tp[r];
    }
    __syncthreads();
    if (t < RANK) tvec[t] = tred[0][t] + tred[1][t] + tred[2][t] + tred[3][t];
    __syncthreads();

    const float* Bm = LB + (size_t)e * H_DIM * RANK;
    #pragma unroll
    for (int j = 0; j < 8; j++) {
      int h = t * 8 + j;
      const float* brow = Bm + h * RANK;
      float s = 0.f;
      #pragma unroll
      for (int r = 0; r < RANK; r += 4) {
        float4 b = ((const float4*)(brow + r))[0];
        s += tvec[r]*b.x + tvec[r+1]*b.y + tvec[r+2]*b.z + tvec[r+3]*b.w;
      }
      outv[j] = LORA_SCALE * s;
    }
  }
  float4* dst = (float4*)(lora_out + (size_t)token * H_DIM + t * 8);
  dst[0] = make_float4(outv[0], outv[1], outv[2], outv[3]);
  dst[1] = make_float4(outv[4], outv[5], outv[6], outv[7]);
}

// ---------------------------------------------------------------------------
// Kernel 2: act = gelu(X @ Wg^T) * (X @ Wu^T)   [128x128 tile, bf16 MFMA]
// XOR-swizzled LDS: LDS slot (row, sub) holds global chunk (row, sub^((row>>1)&3)).
// Staging permutes the GLOBAL subchunk (stays in the same 64B line, coalescing
// intact, global_load_lds uniform-base+lane*16 layout unchanged); fragment
// reads apply the same XOR -> all ds_read_b128 groups hit 8 distinct 16B
// bank-classes (was 2) -> bank conflicts eliminated.
// ---------------------------------------------------------------------------
__global__ __launch_bounds__(256, 2) void gemm_gateup_kernel(
    const uint16_t* __restrict__ X,    // [T, H] bf16
    const uint16_t* __restrict__ Wg,   // [I, H] bf16
    const uint16_t* __restrict__ Wu,   // [I, H] bf16
    uint16_t* __restrict__ act)        // [T, I] bf16
{
  const int K = H_DIM;
  __shared__ __align__(16) uint16_t sa[128 * 32];
  __shared__ __align__(16) uint16_t sg[128 * 32];
  __shared__ __align__(16) uint16_t su[128 * 32];

  const int t = threadIdx.x;
  const int m0 = blockIdx.y * 128;
  const int n0 = blockIdx.x * 128;
  const int lane = t & 63;
  const int wid = t >> 6;
  const int wm = (wid >> 1) * 64;
  const int wn = (wid & 1) * 64;
  const int fr = lane & 15;

  // staging: chunk c -> row=c>>2, LDS slot=c&3, global sub = slot ^ ((row>>1)&3)
  const int c0 = t, c1 = t + 256;
  const int r0 = c0 >> 2, ss0 = (c0 & 3) ^ ((r0 >> 1) & 3);
  const int r1 = c1 >> 2, ss1 = (c1 & 3) ^ ((r1 >> 1) & 3);
  const uint16_t* ga0 = X  + (size_t)(m0 + r0) * K + ss0 * 8;
  const uint16_t* ga1 = X  + (size_t)(m0 + r1) * K + ss1 * 8;
  const uint16_t* gg0 = Wg + (size_t)(n0 + r0) * K + ss0 * 8;
  const uint16_t* gg1 = Wg + (size_t)(n0 + r1) * K + ss1 * 8;
  const uint16_t* gu0 = Wu + (size_t)(n0 + r0) * K + ss0 * 8;
  const uint16_t* gu1 = Wu + (size_t)(n0 + r1) * K + ss1 * 8;

  // fragment read: global sub s=(lane>>4) at row base+fr -> LDS slot s^((fr>>1)&3)
  const int fsw = (((lane >> 4) ^ ((fr >> 1) & 3)) * 8);

  f32x4 accg[4][4], accu[4][4];
  #pragma unroll
  for (int i = 0; i < 4; i++)
    #pragma unroll
    for (int j = 0; j < 4; j++) {
      accg[i][j] = (f32x4){0.f, 0.f, 0.f, 0.f};
      accu[i][j] = (f32x4){0.f, 0.f, 0.f, 0.f};
    }

  for (int k0 = 0; k0 < K; k0 += 32) {
    __syncthreads();
    __builtin_amdgcn_global_load_lds((gv_t*)ga0, (lv_t*)(sa + c0 * 8), 16, 0, 0);
    __builtin_amdgcn_global_load_lds((gv_t*)ga1, (lv_t*)(sa + c1 * 8), 16, 0, 0);
    __builtin_amdgcn_global_load_lds((gv_t*)gg0, (lv_t*)(sg + c0 * 8), 16, 0, 0);
    __builtin_amdgcn_global_load_lds((gv_t*)gg1, (lv_t*)(sg + c1 * 8), 16, 0, 0);
    __builtin_amdgcn_global_load_lds((gv_t*)gu0, (lv_t*)(su + c0 * 8), 16, 0, 0);
    __builtin_amdgcn_global_load_lds((gv_t*)gu1, (lv_t*)(su + c1 * 8), 16, 0, 0);
    ga0 += 32; ga1 += 32; gg0 += 32; gg1 += 32; gu0 += 32; gu1 += 32;
    __syncthreads();

    bf16x8 af[4], gf[4], uf[4];
    #pragma unroll
    for (int mi = 0; mi < 4; mi++)
      af[mi] = *(const bf16x8*)(sa + (wm + mi * 16 + fr) * 32 + fsw);
    #pragma unroll
    for (int ni = 0; ni < 4; ni++) {
      gf[ni] = *(const bf16x8*)(sg + (wn + ni * 16 + fr) * 32 + fsw);
      uf[ni] = *(const bf16x8*)(su + (wn + ni * 16 + fr) * 32 + fsw);
    }
    #pragma unroll
    for (int mi = 0; mi < 4; mi++)
      #pragma unroll
      for (int ni = 0; ni < 4; ni++) {
        accg[mi][ni] = __builtin_amdgcn_mfma_f32_16x16x32_bf16(af[mi], gf[ni], accg[mi][ni], 0, 0, 0);
        accu[mi][ni] = __builtin_amdgcn_mfma_f32_16x16x32_bf16(af[mi], uf[ni], accu[mi][ni], 0, 0, 0);
      }
  }

  // C/D layout: col = lane&15, row = (lane>>4)*4 + reg  [m89-verified]
  const int rbase = (lane >> 4) * 4;
  const int cbase = lane & 15;
  #pragma unroll
  for (int mi = 0; mi < 4; mi++)
    #pragma unroll
    for (int ni = 0; ni < 4; ni++)
      #pragma unroll
      for (int i = 0; i < 4; i++) {
        int row = m0 + wm + mi * 16 + rbase + i;
        int col = n0 + wn + ni * 16 + cbase;
        float g = accg[mi][ni][i];
        float u = accu[mi][ni][i];
        act[(size_t)row * I_DIM + col] = f2bf(gelu_fast(g) * u);
      }
}

// ---------------------------------------------------------------------------
// Kernel 3: out = act @ Wd^T + lora   (Wd stored [H, I] == B^T form)
// Same XOR-swizzled LDS. `out` holds lora on entry (read-then-overwrite
// per element by the same thread).
// ---------------------------------------------------------------------------
__global__ __launch_bounds__(256, 2) void gemm_down_kernel(
    const uint16_t* __restrict__ Act,  // [T, I] bf16
    const uint16_t* __restrict__ Wd,   // [H, I] bf16
    float* __restrict__ out)           // [T, H] fp32
{
  const int K = I_DIM;
  __shared__ __align__(16) uint16_t sa[128 * 32];
  __shared__ __align__(16) uint16_t sb[128 * 32];

  const int t = threadIdx.x;
  const int m0 = blockIdx.y * 128;
  const int n0 = blockIdx.x * 128;
  const int lane = t & 63;
  const int wid = t >> 6;
  const int wm = (wid >> 1) * 64;
  const int wn = (wid & 1) * 64;
  const int fr = lane & 15;

  const int c0 = t, c1 = t + 256;
  const int r0 = c0 >> 2, ss0 = (c0 & 3) ^ ((r0 >> 1) & 3);
  const int r1 = c1 >> 2, ss1 = (c1 & 3) ^ ((r1 >> 1) & 3);
  const uint16_t* ga0 = Act + (size_t)(m0 + r0) * K + ss0 * 8;
  const uint16_t* ga1 = Act + (size_t)(m0 + r1) * K + ss1 * 8;
  const uint16_t* gb0 = Wd  + (size_t)(n0 + r0) * K + ss0 * 8;
  const uint16_t* gb1 = Wd  + (size_t)(n0 + r1) * K + ss1 * 8;

  const int fsw = (((lane >> 4) ^ ((fr >> 1) & 3)) * 8);

  f32x4 acc[4][4];
  #pragma unroll
  for (int i = 0; i < 4; i++)
    #pragma unroll
    for (int j = 0; j < 4; j++) acc[i][j] = (f32x4){0.f, 0.f, 0.f, 0.f};

  for (int k0 = 0; k0 < K; k0 += 32) {
    __syncthreads();
    __builtin_amdgcn_global_load_lds((gv_t*)ga0, (lv_t*)(sa + c0 * 8), 16, 0, 0);
    __builtin_amdgcn_global_load_lds((gv_t*)ga1, (lv_t*)(sa + c1 * 8), 16, 0, 0);
    __builtin_amdgcn_global_load_lds((gv_t*)gb0, (lv_t*)(sb + c0 * 8), 16, 0, 0);
    __builtin_amdgcn_global_load_lds((gv_t*)gb1, (lv_t*)(sb + c1 * 8), 16, 0, 0);
    ga0 += 32; ga1 += 32; gb0 += 32; gb1 += 32;
    __syncthreads();

    bf16x8 af[4], bfr[4];
    #pragma unroll
    for (int mi = 0; mi < 4; mi++)
      af[mi] = *(const bf16x8*)(sa + (wm + mi * 16 + fr) * 32 + fsw);
    #pragma unroll
    for (int ni = 0; ni < 4; ni++)
      bfr[ni] = *(const bf16x8*)(sb + (wn + ni * 16 + fr) * 32 + fsw);
    #pragma unroll
    for (int mi = 0; mi < 4; mi++)
      #pragma unroll
      for (int ni = 0; ni < 4; ni++)
        acc[mi][ni] = __builtin_amdgcn_mfma_f32_16x16x32_bf16(af[mi], bfr[ni], acc[mi][ni], 0, 0, 0);
  }

  const int rbase = (lane >> 4) * 4;
  const int cbase = lane & 15;
  #pragma unroll
  for (int mi = 0; mi < 4; mi++)
    #pragma unroll
    for (int ni = 0; ni < 4; ni++)
      #pragma unroll
      for (int i = 0; i < 4; i++) {
        int row = m0 + wm + mi * 16 + rbase + i;
        int col = n0 + wn + ni * 16 + cbase;
        size_t idx = (size_t)row * H_DIM + col;
        out[idx] = acc[mi][ni][i] + out[idx];
      }
}

// ---------------------------------------------------------------------------
// Kernel 4: aux loss scalar (fp32)
// ---------------------------------------------------------------------------
__global__ void aux_kernel(const float* __restrict__ accum,
                           float* __restrict__ out_aux)
{
  if (threadIdx.x == 0 && blockIdx.x == 0) {
    float s = 0.f;
    #pragma unroll
    for (int e = 0; e < NEXP; e++)
      s += (accum[e] / (float)T_TOKENS) * (accum[NEXP + e] / (float)T_TOKENS);
    out_aux[0] = s * (float)NEXP * 0.01f;
  }
}

// ---------------------------------------------------------------------------
extern "C" void kernel_launch(void* const* d_in, const int* in_sizes, int n_in,
                              void* d_out, int out_size, void* d_ws, size_t ws_size,
                              hipStream_t stream) {
  const float* X  = (const float*)d_in[0];  // hidden_states [4,2048,2048] fp32
  const float* RW = (const float*)d_in[1];  // router_w [5,2048]
  const float* Wg = (const float*)d_in[2];  // gate_w [16384,2048]
  const float* Wu = (const float*)d_in[3];  // up_w [16384,2048]
  const float* Wd = (const float*)d_in[4];  // down_w [2048,16384]
  const float* LA = (const float*)d_in[5];  // lora_A [4,16,2048]
  const float* LB = (const float*)d_in[6];  // lora_B [4,2048,16]
  float* out = (float*)d_out;               // [4,2048,2048] fp32 + 1 aux

  char* ws = (char*)d_ws;
  uint16_t* Xb    = (uint16_t*)(ws);                         // 32 MiB bf16 [T,H]
  uint16_t* Wgb   = (uint16_t*)(ws + (size_t)32  * 1048576); // 64 MiB bf16 [I,H]
  uint16_t* Wub   = (uint16_t*)(ws + (size_t)96  * 1048576); // 64 MiB
  uint16_t* Wdb   = (uint16_t*)(ws + (size_t)160 * 1048576); // 64 MiB [H,I]
  uint16_t* act   = (uint16_t*)(ws + (size_t)224 * 1048576); // 256 MiB bf16 [T,I]
  float*    accum = (float*)   (ws + (size_t)480 * 1048576); // 16 floats

  hipMemsetAsync(accum, 0, 16 * sizeof(float), stream);

  const int nW = I_DIM * H_DIM;
  cvt_kernel<<<nW / 8 / 256, 256, 0, stream>>>(Wg, Wgb, nW / 8);
  cvt_kernel<<<nW / 8 / 256, 256, 0, stream>>>(Wu, Wub, nW / 8);
  cvt_kernel<<<nW / 8 / 256, 256, 0, stream>>>(Wd, Wdb, nW / 8);

  router_lora_kernel<<<T_TOKENS, 256, 0, stream>>>(X, RW, LA, LB, out, Xb, accum);
  gemm_gateup_kernel<<<dim3(I_DIM / 128, T_TOKENS / 128), 256, 0, stream>>>(Xb, Wgb, Wub, act);
  gemm_down_kernel<<<dim3(H_DIM / 128, T_TOKENS / 128), 256, 0, stream>>>(act, Wdb, out);
  aux_kernel<<<1, 64, 0, stream>>>(accum, out + (size_t)T_TOKENS * H_DIM);
}